// Round 4
// baseline (444.337 us; speedup 1.0000x reference)
//
#include <hip/hip_runtime.h>
#include <math.h>

typedef float f4 __attribute__((ext_vector_type(4)));
typedef float f8 __attribute__((ext_vector_type(8)));
typedef _Float16 h8 __attribute__((ext_vector_type(8)));
typedef int i4 __attribute__((ext_vector_type(4)));

// ---------------- graph build ----------------
// CSR with 4 SOURCE-RANGE BUCKETS per row, each bucket padded to a multiple
// of 4 edges. Edges store only the source column (4 B): symmetric
// normalization is factored out via the scaled iterate z = dinv .* y.
// Padding slots point at sentinel row N (kept all-zero in gather buffers).
// Buckets partition sources into 4 contiguous ranges (~3.2 MB of z each) so
// the hop kernel can process them in temporal phases that fit per-XCD L2.

__global__ void k_count(const int* __restrict__ src, const int* __restrict__ dst,
                        int* __restrict__ cnt, float invb, int E) {
  int e = blockIdx.x * blockDim.x + threadIdx.x;
  if (e < E) {
    int b = (int)((float)src[e] * invb);
    b = b > 3 ? 3 : b;
    atomicAdd(&cnt[dst[e] * 4 + b], 1);
  }
}

// scan over 4N bucket entries (padded capacities); also dinv per row
__global__ void k_scan_partial(const int* __restrict__ cnt, int* __restrict__ rowptr,
                               int* __restrict__ bsums, float* __restrict__ dinv,
                               float* __restrict__ rdinv, int N) {
  __shared__ int s[1024];
  int tid = threadIdx.x;
  int idx = blockIdx.x * 1024 + tid;
  int M = 4 * N;
  int v = (idx < M) ? cnt[idx] : 0;
  if (idx < N) {
    int deg = cnt[4 * idx] + cnt[4 * idx + 1] + cnt[4 * idx + 2] + cnt[4 * idx + 3];
    dinv[idx] = rsqrtf((float)(deg + 1));
    rdinv[idx] = sqrtf((float)(deg + 1));
  }
  int vp = (v + 3) & ~3;  // padded bucket capacity
  s[tid] = vp;
  __syncthreads();
  for (int off = 1; off < 1024; off <<= 1) {
    int add = (tid >= off) ? s[tid - off] : 0;
    __syncthreads();
    s[tid] += add;
    __syncthreads();
  }
  if (idx <= M) rowptr[idx] = s[tid] - vp;
  if (tid == 1023) bsums[blockIdx.x] = s[1023];
}

__global__ void k_scan_sums(int* __restrict__ bsums, int nb) {
  __shared__ int s[1024];
  int tid = threadIdx.x;
  int v = (tid < nb) ? bsums[tid] : 0;
  s[tid] = v;
  __syncthreads();
  for (int off = 1; off < 1024; off <<= 1) {
    int add = (tid >= off) ? s[tid - off] : 0;
    __syncthreads();
    s[tid] += add;
    __syncthreads();
  }
  if (tid < nb) bsums[tid] = s[tid] - v;
}

__global__ void k_add_offsets(int* __restrict__ rowptr, int* __restrict__ cursor,
                              const int* __restrict__ bsums, int N) {
  int idx = blockIdx.x * 1024 + threadIdx.x;
  int M = 4 * N;
  if (idx <= M) {
    int v = rowptr[idx] + bsums[blockIdx.x];
    rowptr[idx] = v;
    if (idx < M) cursor[idx] = v;
  }
}

__global__ void k_scatter(const int* __restrict__ src, const int* __restrict__ dst,
                          int* __restrict__ cursor, int* __restrict__ col,
                          float invb, int E) {
  int e = blockIdx.x * blockDim.x + threadIdx.x;
  if (e < E) {
    int s = src[e];
    int b = (int)((float)s * invb);  // same expression as k_count -> consistent
    b = b > 3 ? 3 : b;
    int slot = atomicAdd(&cursor[dst[e] * 4 + b], 1);
    col[slot] = s;
  }
}

// fill padding slots (cursor[idx]..rowptr[idx+1]) with sentinel row N
__global__ void k_padfill(const int* __restrict__ rowptr, const int* __restrict__ cursor,
                          int* __restrict__ col, int N) {
  int idx = blockIdx.x * blockDim.x + threadIdx.x;
  if (idx < 4 * N) {
    int e = cursor[idx], end = rowptr[idx + 1];
    for (; e < end; ++e) col[e] = N;
  }
}

// xz = fp16(dinv .* x); also zero sentinel row N of xz, z0, z1
__global__ void k_tohalf(const float* __restrict__ x, _Float16* __restrict__ xz,
                         const float* __restrict__ dinv, _Float16* __restrict__ z0,
                         _Float16* __restrict__ z1, int total8) {
  int i = blockIdx.x * blockDim.x + threadIdx.x;
  if (i < total8) {
    float d = dinv[i >> 4];
    f4 a = ((const f4*)x)[i * 2], b = ((const f4*)x)[i * 2 + 1];
    f8 v = {a.x, a.y, a.z, a.w, b.x, b.y, b.z, b.w};
    ((h8*)xz)[i] = __builtin_convertvector(d * v, h8);
  } else if (i < total8 + 48) {
    int k = i - total8;
    h8 zero = {0, 0, 0, 0, 0, 0, 0, 0};
    if (k < 16) ((h8*)xz)[total8 + k] = zero;
    else if (k < 32) ((h8*)z0)[total8 + (k - 16)] = zero;
    else ((h8*)z1)[total8 + (k - 32)] = zero;
  }
}

// ---------------- diffusion (Horner, z-domain, bucket-phased) ---------------
// z_out[r] = gs*dinv[r]^2*(sum_e z_in[col_e] + z_in[r]) + c_j*xz[r]
// 8 groups of 8 lanes per wave: group g -> row (g>>1), feature-half (g&1).
// Outer loop over 4 source buckets: at any instant (nearly) all resident
// blocks gather from the same ~3.2 MB source range -> L2-resident per XCD.
// Row accumulators persist in registers across buckets.
__global__ __launch_bounds__(256) void k_hop(
    const int* __restrict__ rowptr, const int* __restrict__ col,
    const float* __restrict__ dinv, const h8* __restrict__ xz,
    const h8* __restrict__ zin, h8* __restrict__ zout,
    const float* __restrict__ t_ptr, int j, int first, int N) {
  int wave = threadIdx.x >> 6;
  int lane = threadIdx.x & 63;
  int grp = lane >> 3;
  int r = (blockIdx.x * 4 + wave) * 4 + (grp >> 1);
  if (r >= N) return;
  int fl = (lane & 7) + (grp & 1) * 8;  // h8 slot 0..15 within the row
  float t = t_ptr[0];
  float cj = expf(-t);
  for (int i = 1; i <= j; ++i) cj *= t / (float)i;
  float gs = first ? cj * t / (float)(j + 1) : 1.0f;

  auto G = [&](int idx) -> f8 {
    return __builtin_convertvector(zin[(size_t)idx * 16 + fl], f8);
  };

  f8 sA = {0, 0, 0, 0, 0, 0, 0, 0}, sB = sA, sC = sA, sD = sA;
  int base = r * 4;
#pragma unroll
  for (int b = 0; b < 4; ++b) {
    int e = rowptr[base + b], end = rowptr[base + b + 1];  // 4-aligned bucket
    const i4* q = (const i4*)&col[e];
    int n4 = (end - e) >> 2;
    if (n4) {
      i4 p = q[0];
      for (int i = 1; i < n4; ++i) {
        i4 nx = q[i];  // next quad off the critical path
        sA += G(p.x);
        sB += G(p.y);
        sC += G(p.z);
        sD += G(p.w);
        p = nx;
      }
      sA += G(p.x);
      sB += G(p.y);
      sC += G(p.z);
      sD += G(p.w);
    }
  }

  f8 s = (sA + sB) + (sC + sD);
  s += G(r);  // + z_in[r] (self-loop, normalization folded into dinv^2)
  float di = dinv[r];
  float sc = gs * di * di;
  f8 xr = __builtin_convertvector(xz[(size_t)r * 16 + fl], f8);
  s = sc * s + cj * xr;
  zout[(size_t)r * 16 + fl] = __builtin_convertvector(s, h8);
}

// ---------------- epilogue: out = (rdinv .* z) @ W^T + b (MFMA fp16) --------
// W staged as fp16 hi/lo in LDS (2x32 KB), XOR-granule swizzle; A-frags read
// straight from global z16. The rdinv un-scaling is applied to the fp32
// accumulators (exact, no extra fp16 rounding). fp32 accumulate.
__global__ __launch_bounds__(256) void k_matmul(
    const h8* __restrict__ z16, const float* __restrict__ W,
    const float* __restrict__ bias, const float* __restrict__ rdinv,
    float* __restrict__ out, int N) {
  __shared__ h8 whiS[128 * 16];
  __shared__ h8 wloS[128 * 16];
  int tid = threadIdx.x;
  int rblk = blockIdx.x * 128;

#pragma unroll
  for (int it = 0; it < 8; ++it) {
    int idx = it * 256 + tid;
    int n = idx >> 4, g = idx & 15;
    f4 a = *(const f4*)&W[(size_t)n * 128 + g * 8];
    f4 b = *(const f4*)&W[(size_t)n * 128 + g * 8 + 4];
    f8 w = {a.x, a.y, a.z, a.w, b.x, b.y, b.z, b.w};
    h8 hi = __builtin_convertvector(w, h8);
    f8 hir = __builtin_convertvector(hi, f8);
    h8 lo = __builtin_convertvector(w - hir, h8);
    int slot = n * 16 + (g ^ (n & 7));
    whiS[slot] = hi;
    wloS[slot] = lo;
  }
  __syncthreads();

  int wave = tid >> 6, lane = tid & 63;
  int q = lane >> 4, fl = lane & 15;
  int rbase = rblk + wave * 32;

  f4 acc[2][8];
#pragma unroll
  for (int rt = 0; rt < 2; ++rt)
#pragma unroll
    for (int nt = 0; nt < 8; ++nt) acc[rt][nt] = (f4){0.f, 0.f, 0.f, 0.f};

#pragma unroll
  for (int s = 0; s < 4; ++s) {
    h8 aA, aB;
    {
      int r0 = rbase + fl;       if (r0 >= N) r0 = N - 1;
      int r1 = rbase + 16 + fl;  if (r1 >= N) r1 = N - 1;
      aA = z16[(size_t)r0 * 16 + s * 4 + q];
      aB = z16[(size_t)r1 * 16 + s * 4 + q];
    }
#pragma unroll
    for (int nt = 0; nt < 8; ++nt) {
      int n = nt * 16 + fl;
      int slot = n * 16 + ((s * 4 + q) ^ (n & 7));
      h8 bh = whiS[slot];
      h8 bl = wloS[slot];
      acc[0][nt] = __builtin_amdgcn_mfma_f32_16x16x32_f16(aA, bh, acc[0][nt], 0, 0, 0);
      acc[0][nt] = __builtin_amdgcn_mfma_f32_16x16x32_f16(aA, bl, acc[0][nt], 0, 0, 0);
      acc[1][nt] = __builtin_amdgcn_mfma_f32_16x16x32_f16(aB, bh, acc[1][nt], 0, 0, 0);
      acc[1][nt] = __builtin_amdgcn_mfma_f32_16x16x32_f16(aB, bl, acc[1][nt], 0, 0, 0);
    }
  }

#pragma unroll
  for (int rt = 0; rt < 2; ++rt) {
#pragma unroll
    for (int reg = 0; reg < 4; ++reg) {
      int r = rbase + rt * 16 + q * 4 + reg;
      if (r < N) {
        float rd = rdinv[r];
#pragma unroll
        for (int nt = 0; nt < 8; ++nt) {
          out[(size_t)r * 128 + nt * 16 + fl] =
              acc[rt][nt][reg] * rd + bias[nt * 16 + fl];
        }
      }
    }
  }
}

// ---------------- launch ----------------

extern "C" void kernel_launch(void* const* d_in, const int* in_sizes, int n_in,
                              void* d_out, int out_size, void* d_ws, size_t ws_size,
                              hipStream_t stream) {
  const float* x = (const float*)d_in[0];
  const int* ei = (const int*)d_in[1];   // int32! (harness converts integer inputs)
  const float* t = (const float*)d_in[2];
  const float* W = (const float*)d_in[3];
  const float* b = (const float*)d_in[4];
  int N = in_sizes[0] / 128;
  int E = in_sizes[1] / 2;
  const int* srcp = ei;
  const int* dstp = ei + E;
  float* out = (float*)d_out;

  char* ws = (char*)d_ws;
  size_t off = 0;
  auto alloc = [&](size_t bytes) -> void* {
    void* p = ws + off;
    off += (bytes + 255) & ~(size_t)255;
    return p;
  };
  h8*    zh0    = (h8*)alloc((size_t)(N + 1) * 128 * 2);  // fp16 z ping (+sentinel)
  h8*    zh1    = (h8*)alloc((size_t)(N + 1) * 128 * 2);  // fp16 z pong (+sentinel)
  h8*    xz     = (h8*)alloc((size_t)(N + 1) * 128 * 2);  // fp16 dinv.*x (+sentinel)
  int*   cnt    = (int*)alloc((size_t)N * 16);            // 4 buckets per row
  float* dinv   = (float*)alloc((size_t)N * 4);
  float* rdinv  = (float*)alloc((size_t)N * 4);
  int*   rowptr = (int*)alloc((size_t)(4 * N + 1) * 4);
  int*   cursor = (int*)alloc((size_t)N * 16);
  int*   bsums  = (int*)alloc(4096);
  size_t col_bytes = ((size_t)E + 16 * (size_t)N) * 4;  // bucket-padded upper bound
  int*   col    = (int*)alloc(col_bytes);
  (void)ws_size;  // ~45 MB total

  int bsize = (N + 3) >> 2;          // source rows per bucket
  float invb = 1.0f / (float)bsize;  // bucket id = (int)(src * invb), clamped

  int nb_scan = (4 * N + 1 + 1023) / 1024;

  hipMemsetAsync(cnt, 0, (size_t)N * 16, stream);
  k_count<<<(E + 255) / 256, 256, 0, stream>>>(srcp, dstp, cnt, invb, E);
  k_scan_partial<<<nb_scan, 1024, 0, stream>>>(cnt, rowptr, bsums, dinv, rdinv, N);
  k_scan_sums<<<1, 1024, 0, stream>>>(bsums, nb_scan);
  k_add_offsets<<<nb_scan, 1024, 0, stream>>>(rowptr, cursor, bsums, N);
  k_scatter<<<(E + 255) / 256, 256, 0, stream>>>(srcp, dstp, cursor, col, invb, E);
  k_padfill<<<(4 * N + 255) / 256, 256, 0, stream>>>(rowptr, cursor, col, N);
  k_tohalf<<<(N * 16 + 48 + 255) / 256, 256, 0, stream>>>(x, (_Float16*)xz, dinv,
                                                          (_Float16*)zh0, (_Float16*)zh1,
                                                          N * 16);

  // Horner: z <- gs*dinv^2*(A z + z) + c_j xz, j = 9..0; first hop gathers xz.
  int nblk = (N + 15) / 16;  // 16 rows per 256-thread block (4 per wave)
  const h8* zin = xz;
  h8* bufs[2] = {zh0, zh1};
  for (int m = 0; m < 10; ++m) {
    h8* zout = bufs[m & 1];
    k_hop<<<nblk, 256, 0, stream>>>(rowptr, col, dinv, xz, zin, zout,
                                    t, 9 - m, (m == 0) ? 1 : 0, N);
    zin = zout;
  }

  k_matmul<<<(N + 127) / 128, 256, 0, stream>>>(zin, W, b, rdinv, out, N);
}